// Round 1
// baseline (595.706 us; speedup 1.0000x reference)
//
#include <hip/hip_runtime.h>
#include <hip/hip_bf16.h>
#include <cstdint>
#include <cstddef>

#define NN 30000
#define NE 480000
#define NG 128
#define DIN 128
#define DH 256
#define NC 60

// ---------------- CSR build ----------------
__global__ void k_count(const int* __restrict__ dst, int* __restrict__ icnt) {
    int e = blockIdx.x * blockDim.x + threadIdx.x;
    if (e < NE) atomicAdd(&icnt[dst[e]], 1);
}

__global__ void k_dinv(const int* __restrict__ icnt, float* __restrict__ dinv) {
    int v = blockIdx.x * blockDim.x + threadIdx.x;
    if (v < NN) dinv[v] = rsqrtf((float)(icnt[v] + 1));  // +1 self-loop
}

// single-block exclusive scan of icnt -> row_ptr[NN+1]
__global__ __launch_bounds__(1024) void k_scan(const int* __restrict__ icnt,
                                               int* __restrict__ row_ptr) {
    __shared__ int wsum[16];
    __shared__ int carry_s;
    int tid = threadIdx.x;
    int lane = tid & 63, wave = tid >> 6;
    if (tid == 0) carry_s = 0;
    __syncthreads();
    for (int base = 0; base < NN; base += 1024) {
        int c0 = carry_s;
        int i = base + tid;
        int v = (i < NN) ? icnt[i] : 0;
        int s = v;
        #pragma unroll
        for (int off = 1; off < 64; off <<= 1) {
            int n = __shfl_up(s, off, 64);
            if (lane >= off) s += n;
        }
        if (lane == 63) wsum[wave] = s;
        __syncthreads();
        if (wave == 0 && lane < 16) {
            int ws = wsum[lane];
            #pragma unroll
            for (int off = 1; off < 16; off <<= 1) {
                int n = __shfl_up(ws, off, 64);
                if (lane >= off) ws += n;
            }
            wsum[lane] = ws;  // inclusive over wave sums
        }
        __syncthreads();
        int woff = (wave == 0) ? 0 : wsum[wave - 1];
        if (i < NN) row_ptr[i] = c0 + woff + s - v;  // exclusive
        __syncthreads();
        if (tid == 0) carry_s = c0 + wsum[15];
        __syncthreads();
    }
    if (tid == 0) row_ptr[NN] = carry_s;  // == NE
}

__global__ void k_fill(const int* __restrict__ ei, const float* __restrict__ dinv,
                       const int* __restrict__ row_ptr, int* __restrict__ cursor,
                       int* __restrict__ csr_src, float* __restrict__ csr_w) {
    int e = blockIdx.x * blockDim.x + threadIdx.x;
    if (e >= NE) return;
    int s = ei[e];        // edge_index[0]
    int d = ei[NE + e];   // edge_index[1]
    int pos = row_ptr[d] + atomicAdd(&cursor[d], 1);
    csr_src[pos] = s;
    csr_w[pos] = dinv[s] * dinv[d];
}

// ---------------- aggregation: out[v] = act( sum_e w_e*in[src_e] + dinv[v]^2*in[v] + bias ) ----------------
// one wave per node; 64 lanes x (D/64) floats covers a full row
template<int D, bool RELU, bool BIAS>
__global__ __launch_bounds__(256) void k_agg(const float* __restrict__ tin, float* __restrict__ tout,
                      const int* __restrict__ row_ptr, const int* __restrict__ csr_src,
                      const float* __restrict__ csr_w, const float* __restrict__ dinv,
                      const float* __restrict__ bias) {
    constexpr int V = D / 64;
    int node = blockIdx.x * 4 + (threadIdx.x >> 6);
    if (node >= NN) return;
    int lane = threadIdx.x & 63;
    float acc[V];
    #pragma unroll
    for (int u = 0; u < V; u++) acc[u] = 0.f;
    int beg = row_ptr[node], end = row_ptr[node + 1];
    for (int e = beg; e < end; e++) {
        int s = csr_src[e];
        float w = csr_w[e];
        const float* row = tin + (size_t)s * D + lane * V;
        if constexpr (V == 4) {
            float4 r = *(const float4*)row;
            acc[0] = fmaf(w, r.x, acc[0]);
            acc[1] = fmaf(w, r.y, acc[1]);
            acc[2] = fmaf(w, r.z, acc[2]);
            acc[3] = fmaf(w, r.w, acc[3]);
        } else {
            float2 r = *(const float2*)row;
            acc[0] = fmaf(w, r.x, acc[0]);
            acc[1] = fmaf(w, r.y, acc[1]);
        }
    }
    // self-loop
    float dv = dinv[node];
    float sw = dv * dv;
    const float* rowv = tin + (size_t)node * D + lane * V;
    if constexpr (V == 4) {
        float4 r = *(const float4*)rowv;
        acc[0] = fmaf(sw, r.x, acc[0]);
        acc[1] = fmaf(sw, r.y, acc[1]);
        acc[2] = fmaf(sw, r.z, acc[2]);
        acc[3] = fmaf(sw, r.w, acc[3]);
    } else {
        float2 r = *(const float2*)rowv;
        acc[0] = fmaf(sw, r.x, acc[0]);
        acc[1] = fmaf(sw, r.y, acc[1]);
    }
    #pragma unroll
    for (int u = 0; u < V; u++) {
        if (BIAS) acc[u] += bias[lane * V + u];
        if (RELU) acc[u] = fmaxf(acc[u], 0.f);
    }
    float* o = tout + (size_t)node * D + lane * V;
    if constexpr (V == 4) {
        *(float4*)o = make_float4(acc[0], acc[1], acc[2], acc[3]);
    } else {
        *(float2*)o = make_float2(acc[0], acc[1]);
    }
}

// ---------------- fp32 NT GEMM: C[M x 256] = A[M x K] * W[256 x K]^T (+bias, relu) ----------------
// BM=64 BN=64 BK=16, 256 threads, 4x4 per thread
template<int K, bool RELU, bool BIAS>
__global__ __launch_bounds__(256) void k_gemm(const float* __restrict__ A,
        const float* __restrict__ W, const float* __restrict__ bias,
        float* __restrict__ C, int M) {
    __shared__ float As[16][64];
    __shared__ float Ws[16][64];
    int tid = threadIdx.x;
    int bm = blockIdx.x * 64;
    int bn = blockIdx.y * 64;
    int tx = tid & 15;   // n-dir
    int ty = tid >> 4;   // m-dir (0..15)
    int lrow = tid >> 2; // 0..63 (load row)
    int lkq = tid & 3;   // 0..3  (load k-quad)
    float acc[4][4];
    #pragma unroll
    for (int i = 0; i < 4; i++)
        #pragma unroll
        for (int j = 0; j < 4; j++) acc[i][j] = 0.f;

    for (int k0 = 0; k0 < K; k0 += 16) {
        int ar = bm + lrow;
        if (ar >= M) ar = M - 1;  // clamp: garbage ok, store is guarded
        float4 a4 = *(const float4*)(A + (size_t)ar * K + k0 + lkq * 4);
        float4 w4 = *(const float4*)(W + (size_t)(bn + lrow) * K + k0 + lkq * 4);
        __syncthreads();
        As[lkq * 4 + 0][lrow] = a4.x;
        As[lkq * 4 + 1][lrow] = a4.y;
        As[lkq * 4 + 2][lrow] = a4.z;
        As[lkq * 4 + 3][lrow] = a4.w;
        Ws[lkq * 4 + 0][lrow] = w4.x;
        Ws[lkq * 4 + 1][lrow] = w4.y;
        Ws[lkq * 4 + 2][lrow] = w4.z;
        Ws[lkq * 4 + 3][lrow] = w4.w;
        __syncthreads();
        #pragma unroll
        for (int kk = 0; kk < 16; kk++) {
            float4 av = *(const float4*)&As[kk][ty * 4];
            float4 wv = *(const float4*)&Ws[kk][tx * 4];
            float ar_[4] = {av.x, av.y, av.z, av.w};
            float wr_[4] = {wv.x, wv.y, wv.z, wv.w};
            #pragma unroll
            for (int i = 0; i < 4; i++)
                #pragma unroll
                for (int j = 0; j < 4; j++)
                    acc[i][j] = fmaf(ar_[i], wr_[j], acc[i][j]);
        }
    }
    #pragma unroll
    for (int i = 0; i < 4; i++) {
        int r = bm + ty * 4 + i;
        if (r < M) {
            float4 o = make_float4(acc[i][0], acc[i][1], acc[i][2], acc[i][3]);
            if (BIAS) {
                o.x += bias[bn + tx * 4 + 0];
                o.y += bias[bn + tx * 4 + 1];
                o.z += bias[bn + tx * 4 + 2];
                o.w += bias[bn + tx * 4 + 3];
            }
            if (RELU) {
                o.x = fmaxf(o.x, 0.f); o.y = fmaxf(o.y, 0.f);
                o.z = fmaxf(o.z, 0.f); o.w = fmaxf(o.w, 0.f);
            }
            *(float4*)(C + (size_t)r * 256 + bn + tx * 4) = o;
        }
    }
}

// ---------------- mean pool over sorted batch ids ----------------
__global__ __launch_bounds__(256) void k_pool(const float* __restrict__ h, const int* __restrict__ batch,
                       float* __restrict__ pooled) {
    int g = blockIdx.x;
    int lo = 0, hi = NN;
    while (lo < hi) { int mid = (lo + hi) >> 1; if (batch[mid] < g) lo = mid + 1; else hi = mid; }
    int start = lo;
    hi = NN;
    while (lo < hi) { int mid = (lo + hi) >> 1; if (batch[mid] < g + 1) lo = mid + 1; else hi = mid; }
    int end = lo;
    int f = threadIdx.x;  // 256 = DH
    float s = 0.f;
    for (int r = start; r < end; r++) s += h[(size_t)r * DH + f];
    int cnt = end - start;
    pooled[g * DH + f] = (cnt > 0) ? s / (float)cnt : 0.f;
}

// ---------------- FC: out[G x 60] = pooled[G x 256] @ Wfc[60 x 256]^T + bfc ----------------
__global__ __launch_bounds__(64) void k_fc(const float* __restrict__ pooled, const float* __restrict__ Wfc,
                    const float* __restrict__ bfc, float* __restrict__ out) {
    __shared__ float p[DH];
    int g = blockIdx.x;
    int t = threadIdx.x;
    for (int i = t; i < DH; i += 64) p[i] = pooled[g * DH + i];
    __syncthreads();
    if (t < NC) {
        float a = bfc[t];
        for (int k = 0; k < DH; k++) a = fmaf(p[k], Wfc[t * DH + k], a);
        out[g * NC + t] = a;
    }
}

extern "C" void kernel_launch(void* const* d_in, const int* in_sizes, int n_in,
                              void* d_out, int out_size, void* d_ws, size_t ws_size,
                              hipStream_t stream) {
    const float* x     = (const float*)d_in[0];
    const int*   ei    = (const int*)d_in[1];
    const int*   batch = (const int*)d_in[2];
    const float* W1 = (const float*)d_in[3];
    const float* b1 = (const float*)d_in[4];
    const float* W2 = (const float*)d_in[5];
    const float* b2 = (const float*)d_in[6];
    const float* W3 = (const float*)d_in[7];
    const float* b3 = (const float*)d_in[8];
    const float* Wfc = (const float*)d_in[9];
    const float* bfc = (const float*)d_in[10];
    float* out = (float*)d_out;

    char* wp = (char*)d_ws;
    auto alloc = [&](size_t bytes) {
        char* p = wp;
        wp += (bytes + 511) & ~(size_t)511;
        return (void*)p;
    };
    int*   icnt    = (int*)alloc((size_t)NN * 4);
    int*   row_ptr = (int*)alloc((size_t)(NN + 1) * 4);
    int*   cursor  = (int*)alloc((size_t)NN * 4);
    int*   csr_src = (int*)alloc((size_t)NE * 4);
    float* csr_w   = (float*)alloc((size_t)NE * 4);
    float* dinv    = (float*)alloc((size_t)NN * 4);
    float* tbuf    = (float*)alloc((size_t)NN * DH * 4);
    float* hbuf    = (float*)alloc((size_t)NN * DH * 4);
    float* pooled  = (float*)alloc((size_t)NG * DH * 4);

    hipMemsetAsync(icnt, 0, (size_t)NN * 4, stream);
    hipMemsetAsync(cursor, 0, (size_t)NN * 4, stream);

    k_count<<<(NE + 255) / 256, 256, 0, stream>>>(ei + NE, icnt);
    k_dinv<<<(NN + 255) / 256, 256, 0, stream>>>(icnt, dinv);
    k_scan<<<1, 1024, 0, stream>>>(icnt, row_ptr);
    k_fill<<<(NE + 255) / 256, 256, 0, stream>>>(ei, dinv, row_ptr, cursor, csr_src, csr_w);

    dim3 gemm_grid((NN + 63) / 64, 256 / 64);

    // layer 1: aggregate x at 128 dims (linearity reorder), then GEMM+b1+relu
    k_agg<128, false, false><<<NN / 4, 256, 0, stream>>>(x, tbuf, row_ptr, csr_src, csr_w, dinv, nullptr);
    k_gemm<128, true, true><<<gemm_grid, 256, 0, stream>>>(tbuf, W1, b1, hbuf, NN);
    // layer 2: GEMM then aggregate+b2+relu
    k_gemm<256, false, false><<<gemm_grid, 256, 0, stream>>>(hbuf, W2, nullptr, tbuf, NN);
    k_agg<256, true, true><<<NN / 4, 256, 0, stream>>>(tbuf, hbuf, row_ptr, csr_src, csr_w, dinv, b2);
    // layer 3
    k_gemm<256, false, false><<<gemm_grid, 256, 0, stream>>>(hbuf, W3, nullptr, tbuf, NN);
    k_agg<256, true, true><<<NN / 4, 256, 0, stream>>>(tbuf, hbuf, row_ptr, csr_src, csr_w, dinv, b3);

    k_pool<<<NG, 256, 0, stream>>>(hbuf, batch, pooled);
    k_fc<<<NG, 64, 0, stream>>>(pooled, Wfc, bfc, out);
}

// Round 2
// 477.351 us; speedup vs baseline: 1.2479x; 1.2479x over previous
//
#include <hip/hip_runtime.h>
#include <hip/hip_bf16.h>
#include <cstdint>
#include <cstddef>

#define NN 30000
#define NE 480000
#define NG 128
#define DIN 128
#define DH 256
#define NC 60
#define NB 118  // scan blocks: ceil(30000/256)

typedef __bf16 bf16x8 __attribute__((ext_vector_type(8)));
typedef float f32x4 __attribute__((ext_vector_type(4)));

// ---------------- bf16 split helpers (RNE, branchless, finite inputs) ----------------
__device__ __forceinline__ unsigned short f2bf_rne(float f) {
    unsigned int u = __builtin_bit_cast(unsigned int, f);
    u += 0x7fffu + ((u >> 16) & 1u);
    return (unsigned short)(u >> 16);
}
__device__ __forceinline__ float bf2f(unsigned short b) {
    unsigned int u = ((unsigned int)b) << 16;
    return __builtin_bit_cast(float, u);
}
__device__ __forceinline__ void split_bf16(float f, unsigned short& hi, unsigned short& lo) {
    hi = f2bf_rne(f);
    lo = f2bf_rne(f - bf2f(hi));
}

// ---------------- CSR build ----------------
__global__ void k_count(const int* __restrict__ dst, int* __restrict__ icnt) {
    int e = blockIdx.x * blockDim.x + threadIdx.x;
    if (e < NE) atomicAdd(&icnt[dst[e]], 1);
}

__global__ void k_dinv(const int* __restrict__ icnt, float* __restrict__ dinv) {
    int v = blockIdx.x * blockDim.x + threadIdx.x;
    if (v < NN) dinv[v] = rsqrtf((float)(icnt[v] + 1));  // +1 self-loop
}

// scan stage 1: per-block sums of icnt
__global__ __launch_bounds__(256) void k_scan1(const int* __restrict__ icnt, int* __restrict__ psum) {
    __shared__ int ws[4];
    int i = blockIdx.x * 256 + threadIdx.x;
    int lane = threadIdx.x & 63, wv = threadIdx.x >> 6;
    int v = (i < NN) ? icnt[i] : 0;
    #pragma unroll
    for (int off = 32; off > 0; off >>= 1) v += __shfl_down(v, off, 64);
    if (lane == 0) ws[wv] = v;
    __syncthreads();
    if (threadIdx.x == 0) psum[blockIdx.x] = ws[0] + ws[1] + ws[2] + ws[3];
}

// scan stage 2: exclusive scan of NB partial sums (1 wave)
__global__ __launch_bounds__(64) void k_scan2(const int* __restrict__ psum, int* __restrict__ poff) {
    int lane = threadIdx.x;
    int carry = 0;
    for (int base = 0; base < NB; base += 64) {
        int i = base + lane;
        int v = (i < NB) ? psum[i] : 0;
        int s = v;
        #pragma unroll
        for (int off = 1; off < 64; off <<= 1) {
            int n = __shfl_up(s, off, 64);
            if (lane >= off) s += n;
        }
        if (i < NB) poff[i] = carry + s - v;
        carry += __shfl(s, 63, 64);
    }
}

// scan stage 3: row_ptr = poff[b] + exclusive within block
__global__ __launch_bounds__(256) void k_scan3(const int* __restrict__ icnt, const int* __restrict__ poff,
                                               int* __restrict__ row_ptr) {
    __shared__ int ws[4];
    int i = blockIdx.x * 256 + threadIdx.x;
    int lane = threadIdx.x & 63, wv = threadIdx.x >> 6;
    int v = (i < NN) ? icnt[i] : 0;
    int s = v;
    #pragma unroll
    for (int off = 1; off < 64; off <<= 1) {
        int n = __shfl_up(s, off, 64);
        if (lane >= off) s += n;
    }
    if (lane == 63) ws[wv] = s;
    __syncthreads();
    int add = 0;
    for (int j = 0; j < wv; j++) add += ws[j];
    if (i < NN) row_ptr[i] = poff[blockIdx.x] + add + s - v;
    if (blockIdx.x == 0 && threadIdx.x == 0) row_ptr[NN] = NE;
}

__global__ void k_fill(const int* __restrict__ ei, const float* __restrict__ dinv,
                       const int* __restrict__ row_ptr, int* __restrict__ cursor,
                       int* __restrict__ csr_src, float* __restrict__ csr_w) {
    int e = blockIdx.x * blockDim.x + threadIdx.x;
    if (e >= NE) return;
    int s = ei[e];        // edge_index[0]
    int d = ei[NE + e];   // edge_index[1]
    int pos = row_ptr[d] + atomicAdd(&cursor[d], 1);
    csr_src[pos] = s;
    csr_w[pos] = dinv[s] * dinv[d];
}

// ---------------- W split: fp32 -> bf16 hi/lo ----------------
__global__ void k_wsplit(const float* __restrict__ W, unsigned short* __restrict__ Wh,
                         unsigned short* __restrict__ Wl, int n) {
    int i = blockIdx.x * blockDim.x + threadIdx.x;
    if (i < n) split_bf16(W[i], Wh[i], Wl[i]);
}

// ---------------- aggregation: u[v] = sum_e w_e*in[src_e] + dinv[v]^2*in[v] ----------------
// one wave per node; outputs bf16 hi/lo split (feeds MFMA GEMM). edge loop unrolled x2.
template<int D>
__global__ __launch_bounds__(256) void k_agg(const float* __restrict__ tin,
                      unsigned short* __restrict__ th, unsigned short* __restrict__ tl,
                      const int* __restrict__ row_ptr, const int* __restrict__ csr_src,
                      const float* __restrict__ csr_w, const float* __restrict__ dinv) {
    constexpr int V = D / 64;
    int node = blockIdx.x * 4 + (threadIdx.x >> 6);
    int lane = threadIdx.x & 63;
    float acc[V];
    #pragma unroll
    for (int u = 0; u < V; u++) acc[u] = 0.f;
    int beg = row_ptr[node], end = row_ptr[node + 1];
    int e = beg;
    if constexpr (V == 4) {
        for (; e + 2 <= end; e += 2) {
            int s0 = csr_src[e], s1 = csr_src[e + 1];
            float w0 = csr_w[e], w1 = csr_w[e + 1];
            float4 r0 = *(const float4*)(tin + (size_t)s0 * D + lane * 4);
            float4 r1 = *(const float4*)(tin + (size_t)s1 * D + lane * 4);
            acc[0] = fmaf(w0, r0.x, fmaf(w1, r1.x, acc[0]));
            acc[1] = fmaf(w0, r0.y, fmaf(w1, r1.y, acc[1]));
            acc[2] = fmaf(w0, r0.z, fmaf(w1, r1.z, acc[2]));
            acc[3] = fmaf(w0, r0.w, fmaf(w1, r1.w, acc[3]));
        }
        if (e < end) {
            int s0 = csr_src[e];
            float w0 = csr_w[e];
            float4 r0 = *(const float4*)(tin + (size_t)s0 * D + lane * 4);
            acc[0] = fmaf(w0, r0.x, acc[0]);
            acc[1] = fmaf(w0, r0.y, acc[1]);
            acc[2] = fmaf(w0, r0.z, acc[2]);
            acc[3] = fmaf(w0, r0.w, acc[3]);
        }
        float dv = dinv[node];
        float sw = dv * dv;
        float4 rv = *(const float4*)(tin + (size_t)node * D + lane * 4);
        acc[0] = fmaf(sw, rv.x, acc[0]);
        acc[1] = fmaf(sw, rv.y, acc[1]);
        acc[2] = fmaf(sw, rv.z, acc[2]);
        acc[3] = fmaf(sw, rv.w, acc[3]);
        ushort4 h4, l4;
        split_bf16(acc[0], h4.x, l4.x);
        split_bf16(acc[1], h4.y, l4.y);
        split_bf16(acc[2], h4.z, l4.z);
        split_bf16(acc[3], h4.w, l4.w);
        size_t o = (size_t)node * D + lane * 4;
        *(ushort4*)(th + o) = h4;
        *(ushort4*)(tl + o) = l4;
    } else {
        for (; e + 2 <= end; e += 2) {
            int s0 = csr_src[e], s1 = csr_src[e + 1];
            float w0 = csr_w[e], w1 = csr_w[e + 1];
            float2 r0 = *(const float2*)(tin + (size_t)s0 * D + lane * 2);
            float2 r1 = *(const float2*)(tin + (size_t)s1 * D + lane * 2);
            acc[0] = fmaf(w0, r0.x, fmaf(w1, r1.x, acc[0]));
            acc[1] = fmaf(w0, r0.y, fmaf(w1, r1.y, acc[1]));
        }
        if (e < end) {
            int s0 = csr_src[e];
            float w0 = csr_w[e];
            float2 r0 = *(const float2*)(tin + (size_t)s0 * D + lane * 2);
            acc[0] = fmaf(w0, r0.x, acc[0]);
            acc[1] = fmaf(w0, r0.y, acc[1]);
        }
        float dv = dinv[node];
        float sw = dv * dv;
        float2 rv = *(const float2*)(tin + (size_t)node * D + lane * 2);
        acc[0] = fmaf(sw, rv.x, acc[0]);
        acc[1] = fmaf(sw, rv.y, acc[1]);
        ushort2 h2, l2;
        split_bf16(acc[0], h2.x, l2.x);
        split_bf16(acc[1], h2.y, l2.y);
        size_t o = (size_t)node * D + lane * 2;
        *(ushort2*)(th + o) = h2;
        *(ushort2*)(tl + o) = l2;
    }
}

// ---------------- split-bf16 MFMA GEMM: C[M x 256] = relu(A * W^T + bias) ----------------
// A given as hi/lo bf16 [M x K]; W as hi/lo bf16 [256 x K] (both K-contiguous, NT).
// Block 256 threads (4 waves), tile BM=128 x BN=64, BK=32. Wave = 64x32 = 4x2 tiles of 16x16.
// A*W ~= Ah*Wh + Ah*Wl + Al*Wh  (Al*Wl dropped, ~2^-16 relative)
template<int K>
__global__ __launch_bounds__(256) void k_gemm(const unsigned short* __restrict__ Ah,
        const unsigned short* __restrict__ Al,
        const unsigned short* __restrict__ Wh, const unsigned short* __restrict__ Wl,
        const float* __restrict__ bias, float* __restrict__ C, int M) {
    __shared__ unsigned short lsAh[128 * 32];
    __shared__ unsigned short lsAl[128 * 32];
    __shared__ unsigned short lsBh[64 * 32];
    __shared__ unsigned short lsBl[64 * 32];
    int t = threadIdx.x;
    int bm = blockIdx.x * 128;
    int bn = blockIdx.y * 64;
    int lane = t & 63, wv = t >> 6;
    int wm = (wv & 1) * 64;       // wave m-offset in block
    int wn = (wv >> 1) * 32;      // wave n-offset in block
    int lm = lane & 15, q = lane >> 4;
    // staging roles
    int r4 = t >> 2;   // 0..63
    int c4 = t & 3;    // 16B chunk (8 bf16)
    int ra0 = bm + r4;       if (ra0 >= M) ra0 = M - 1;
    int ra1 = bm + 64 + r4;  if (ra1 >= M) ra1 = M - 1;
    int rb  = bn + r4;       // < 256 always

    f32x4 acc[4][2];
    #pragma unroll
    for (int i = 0; i < 4; i++)
        #pragma unroll
        for (int j = 0; j < 2; j++) acc[i][j] = (f32x4){0.f, 0.f, 0.f, 0.f};

    for (int k0 = 0; k0 < K; k0 += 32) {
        size_t ko = (size_t)k0 + c4 * 8;
        uint4 ah0 = *(const uint4*)(Ah + (size_t)ra0 * K + ko);
        uint4 ah1 = *(const uint4*)(Ah + (size_t)ra1 * K + ko);
        uint4 al0 = *(const uint4*)(Al + (size_t)ra0 * K + ko);
        uint4 al1 = *(const uint4*)(Al + (size_t)ra1 * K + ko);
        uint4 bh  = *(const uint4*)(Wh + (size_t)rb * K + ko);
        uint4 bl  = *(const uint4*)(Wl + (size_t)rb * K + ko);
        __syncthreads();  // previous tile fully consumed
        *(uint4*)&lsAh[(r4) * 32 + c4 * 8] = ah0;
        *(uint4*)&lsAh[(64 + r4) * 32 + c4 * 8] = ah1;
        *(uint4*)&lsAl[(r4) * 32 + c4 * 8] = al0;
        *(uint4*)&lsAl[(64 + r4) * 32 + c4 * 8] = al1;
        *(uint4*)&lsBh[r4 * 32 + c4 * 8] = bh;
        *(uint4*)&lsBl[r4 * 32 + c4 * 8] = bl;
        __syncthreads();  // tile staged
        bf16x8 bfh[2], bfl[2];
        #pragma unroll
        for (int nt = 0; nt < 2; nt++) {
            bfh[nt] = *(const bf16x8*)&lsBh[(wn + nt * 16 + lm) * 32 + q * 8];
            bfl[nt] = *(const bf16x8*)&lsBl[(wn + nt * 16 + lm) * 32 + q * 8];
        }
        #pragma unroll
        for (int mt = 0; mt < 4; mt++) {
            bf16x8 afh = *(const bf16x8*)&lsAh[(wm + mt * 16 + lm) * 32 + q * 8];
            bf16x8 afl = *(const bf16x8*)&lsAl[(wm + mt * 16 + lm) * 32 + q * 8];
            #pragma unroll
            for (int nt = 0; nt < 2; nt++) {
                acc[mt][nt] = __builtin_amdgcn_mfma_f32_16x16x32_bf16(afh, bfh[nt], acc[mt][nt], 0, 0, 0);
                acc[mt][nt] = __builtin_amdgcn_mfma_f32_16x16x32_bf16(afh, bfl[nt], acc[mt][nt], 0, 0, 0);
                acc[mt][nt] = __builtin_amdgcn_mfma_f32_16x16x32_bf16(afl, bfh[nt], acc[mt][nt], 0, 0, 0);
            }
        }
    }
    // epilogue: C/D layout col = lane&15, row = q*4 + r
    #pragma unroll
    for (int mt = 0; mt < 4; mt++) {
        #pragma unroll
        for (int nt = 0; nt < 2; nt++) {
            int col = bn + wn + nt * 16 + lm;
            float bv = bias[col];
            #pragma unroll
            for (int r = 0; r < 4; r++) {
                int row = bm + wm + mt * 16 + q * 4 + r;
                if (row < M) {
                    float v = acc[mt][nt][r] + bv;
                    C[(size_t)row * 256 + col] = fmaxf(v, 0.f);
                }
            }
        }
    }
}

// ---------------- mean pool over sorted batch ids ----------------
__global__ __launch_bounds__(256) void k_pool(const float* __restrict__ h, const int* __restrict__ batch,
                       float* __restrict__ pooled) {
    int g = blockIdx.x;
    int lo = 0, hi = NN;
    while (lo < hi) { int mid = (lo + hi) >> 1; if (batch[mid] < g) lo = mid + 1; else hi = mid; }
    int start = lo;
    hi = NN;
    while (lo < hi) { int mid = (lo + hi) >> 1; if (batch[mid] < g + 1) lo = mid + 1; else hi = mid; }
    int end = lo;
    int f = threadIdx.x;  // 256 = DH
    float s = 0.f;
    for (int r = start; r < end; r++) s += h[(size_t)r * DH + f];
    int cnt = end - start;
    pooled[g * DH + f] = (cnt > 0) ? s / (float)cnt : 0.f;
}

// ---------------- FC: out[G x 60] = pooled[G x 256] @ Wfc[60 x 256]^T + bfc ----------------
__global__ __launch_bounds__(64) void k_fc(const float* __restrict__ pooled, const float* __restrict__ Wfc,
                    const float* __restrict__ bfc, float* __restrict__ out) {
    __shared__ float p[DH];
    int g = blockIdx.x;
    int t = threadIdx.x;
    for (int i = t; i < DH; i += 64) p[i] = pooled[g * DH + i];
    __syncthreads();
    if (t < NC) {
        float a = bfc[t];
        for (int k = 0; k < DH; k++) a = fmaf(p[k], Wfc[t * DH + k], a);
        out[g * NC + t] = a;
    }
}

extern "C" void kernel_launch(void* const* d_in, const int* in_sizes, int n_in,
                              void* d_out, int out_size, void* d_ws, size_t ws_size,
                              hipStream_t stream) {
    const float* x     = (const float*)d_in[0];
    const int*   ei    = (const int*)d_in[1];
    const int*   batch = (const int*)d_in[2];
    const float* W1 = (const float*)d_in[3];
    const float* b1 = (const float*)d_in[4];
    const float* W2 = (const float*)d_in[5];
    const float* b2 = (const float*)d_in[6];
    const float* W3 = (const float*)d_in[7];
    const float* b3 = (const float*)d_in[8];
    const float* Wfc = (const float*)d_in[9];
    const float* bfc = (const float*)d_in[10];
    float* out = (float*)d_out;

    char* wp = (char*)d_ws;
    auto alloc = [&](size_t bytes) {
        char* p = wp;
        wp += (bytes + 511) & ~(size_t)511;
        return (void*)p;
    };
    int*   icnt    = (int*)alloc((size_t)NN * 4);
    int*   row_ptr = (int*)alloc((size_t)(NN + 1) * 4);
    int*   cursor  = (int*)alloc((size_t)NN * 4);
    int*   psum    = (int*)alloc((size_t)NB * 4);
    int*   poff    = (int*)alloc((size_t)NB * 4);
    int*   csr_src = (int*)alloc((size_t)NE * 4);
    float* csr_w   = (float*)alloc((size_t)NE * 4);
    float* dinv    = (float*)alloc((size_t)NN * 4);
    unsigned short* th = (unsigned short*)alloc((size_t)NN * DH * 2);
    unsigned short* tl = (unsigned short*)alloc((size_t)NN * DH * 2);
    float* hbuf    = (float*)alloc((size_t)NN * DH * 4);
    unsigned short* w1h = (unsigned short*)alloc((size_t)DH * DIN * 2);
    unsigned short* w1l = (unsigned short*)alloc((size_t)DH * DIN * 2);
    unsigned short* w2h = (unsigned short*)alloc((size_t)DH * DH * 2);
    unsigned short* w2l = (unsigned short*)alloc((size_t)DH * DH * 2);
    unsigned short* w3h = (unsigned short*)alloc((size_t)DH * DH * 2);
    unsigned short* w3l = (unsigned short*)alloc((size_t)DH * DH * 2);
    float* pooled  = (float*)alloc((size_t)NG * DH * 4);

    hipMemsetAsync(icnt, 0, (size_t)NN * 4, stream);
    hipMemsetAsync(cursor, 0, (size_t)NN * 4, stream);

    k_count<<<(NE + 255) / 256, 256, 0, stream>>>(ei + NE, icnt);
    k_dinv<<<(NN + 255) / 256, 256, 0, stream>>>(icnt, dinv);
    k_scan1<<<NB, 256, 0, stream>>>(icnt, psum);
    k_scan2<<<1, 64, 0, stream>>>(psum, poff);
    k_scan3<<<NB, 256, 0, stream>>>(icnt, poff, row_ptr);
    k_fill<<<(NE + 255) / 256, 256, 0, stream>>>(ei, dinv, row_ptr, cursor, csr_src, csr_w);

    k_wsplit<<<(DH * DIN + 255) / 256, 256, 0, stream>>>(W1, w1h, w1l, DH * DIN);
    k_wsplit<<<(DH * DH + 255) / 256, 256, 0, stream>>>(W2, w2h, w2l, DH * DH);
    k_wsplit<<<(DH * DH + 255) / 256, 256, 0, stream>>>(W3, w3h, w3l, DH * DH);

    dim3 gemm_grid((NN + 127) / 128, 4);

    // all layers: h_l = relu((A.h_{l-1}) W^T + b)  [linearity reorder]
    k_agg<128><<<NN / 4, 256, 0, stream>>>(x, th, tl, row_ptr, csr_src, csr_w, dinv);
    k_gemm<128><<<gemm_grid, 256, 0, stream>>>(th, tl, w1h, w1l, b1, hbuf, NN);
    k_agg<256><<<NN / 4, 256, 0, stream>>>(hbuf, th, tl, row_ptr, csr_src, csr_w, dinv);
    k_gemm<256><<<gemm_grid, 256, 0, stream>>>(th, tl, w2h, w2l, b2, hbuf, NN);
    k_agg<256><<<NN / 4, 256, 0, stream>>>(hbuf, th, tl, row_ptr, csr_src, csr_w, dinv);
    k_gemm<256><<<gemm_grid, 256, 0, stream>>>(th, tl, w3h, w3l, b3, hbuf, NN);

    k_pool<<<NG, 256, 0, stream>>>(hbuf, batch, pooled);
    k_fc<<<NG, 64, 0, stream>>>(pooled, Wfc, bfc, out);
}

// Round 3
// 402.199 us; speedup vs baseline: 1.4811x; 1.1869x over previous
//
#include <hip/hip_runtime.h>
#include <hip/hip_bf16.h>
#include <cstdint>
#include <cstddef>

#define NN 30000
#define NE 480000
#define NG 128
#define DIN 128
#define DH 256
#define NC 60
#define NB 118  // scan blocks: ceil(30000/256)

typedef __bf16 bf16x8 __attribute__((ext_vector_type(8)));
typedef float f32x4 __attribute__((ext_vector_type(4)));

// ---------------- bf16 helpers (RNE, branchless, finite inputs) ----------------
__device__ __forceinline__ unsigned short f2bf_rne(float f) {
    unsigned int u = __builtin_bit_cast(unsigned int, f);
    u += 0x7fffu + ((u >> 16) & 1u);
    return (unsigned short)(u >> 16);
}
__device__ __forceinline__ float bf2f(unsigned short b) {
    unsigned int u = ((unsigned int)b) << 16;
    return __builtin_bit_cast(float, u);
}
__device__ __forceinline__ void split_bf16(float f, unsigned short& hi, unsigned short& lo) {
    hi = f2bf_rne(f);
    lo = f2bf_rne(f - bf2f(hi));
}

// ---------------- CSR build ----------------
__global__ void k_count(const int* __restrict__ dst, int* __restrict__ icnt) {
    int e = blockIdx.x * blockDim.x + threadIdx.x;
    if (e < NE) atomicAdd(&icnt[dst[e]], 1);
}

__global__ void k_dinv(const int* __restrict__ icnt, float* __restrict__ dinv) {
    int v = blockIdx.x * blockDim.x + threadIdx.x;
    if (v < NN) dinv[v] = rsqrtf((float)(icnt[v] + 1));  // +1 self-loop
}

// scan stage 1: per-block sums of icnt
__global__ __launch_bounds__(256) void k_scan1(const int* __restrict__ icnt, int* __restrict__ psum) {
    __shared__ int ws[4];
    int i = blockIdx.x * 256 + threadIdx.x;
    int lane = threadIdx.x & 63, wv = threadIdx.x >> 6;
    int v = (i < NN) ? icnt[i] : 0;
    #pragma unroll
    for (int off = 32; off > 0; off >>= 1) v += __shfl_down(v, off, 64);
    if (lane == 0) ws[wv] = v;
    __syncthreads();
    if (threadIdx.x == 0) psum[blockIdx.x] = ws[0] + ws[1] + ws[2] + ws[3];
}

// scan stage 2: exclusive scan of NB partial sums (1 wave)
__global__ __launch_bounds__(64) void k_scan2(const int* __restrict__ psum, int* __restrict__ poff) {
    int lane = threadIdx.x;
    int carry = 0;
    for (int base = 0; base < NB; base += 64) {
        int i = base + lane;
        int v = (i < NB) ? psum[i] : 0;
        int s = v;
        #pragma unroll
        for (int off = 1; off < 64; off <<= 1) {
            int n = __shfl_up(s, off, 64);
            if (lane >= off) s += n;
        }
        if (i < NB) poff[i] = carry + s - v;
        carry += __shfl(s, 63, 64);
    }
}

// scan stage 3: row_ptr = poff[b] + exclusive within block
__global__ __launch_bounds__(256) void k_scan3(const int* __restrict__ icnt, const int* __restrict__ poff,
                                               int* __restrict__ row_ptr) {
    __shared__ int ws[4];
    int i = blockIdx.x * 256 + threadIdx.x;
    int lane = threadIdx.x & 63, wv = threadIdx.x >> 6;
    int v = (i < NN) ? icnt[i] : 0;
    int s = v;
    #pragma unroll
    for (int off = 1; off < 64; off <<= 1) {
        int n = __shfl_up(s, off, 64);
        if (lane >= off) s += n;
    }
    if (lane == 63) ws[wv] = s;
    __syncthreads();
    int add = 0;
    for (int j = 0; j < wv; j++) add += ws[j];
    if (i < NN) row_ptr[i] = poff[blockIdx.x] + add + s - v;
    if (blockIdx.x == 0 && threadIdx.x == 0) row_ptr[NN] = NE;
}

__global__ void k_fill(const int* __restrict__ ei, const float* __restrict__ dinv,
                       const int* __restrict__ row_ptr, int* __restrict__ cursor,
                       int* __restrict__ csr_src, float* __restrict__ csr_w) {
    int e = blockIdx.x * blockDim.x + threadIdx.x;
    if (e >= NE) return;
    int s = ei[e];        // edge_index[0]
    int d = ei[NE + e];   // edge_index[1]
    int pos = row_ptr[d] + atomicAdd(&cursor[d], 1);
    csr_src[pos] = s;
    csr_w[pos] = dinv[s] * dinv[d];
}

// ---------------- W split: fp32 -> bf16 hi/lo ----------------
__global__ void k_wsplit(const float* __restrict__ W, unsigned short* __restrict__ Wh,
                         unsigned short* __restrict__ Wl, int n) {
    int i = blockIdx.x * blockDim.x + threadIdx.x;
    if (i < n) split_bf16(W[i], Wh[i], Wl[i]);
}

// ---------------- x: fp32 -> bf16 plane ----------------
__global__ void k_x2bf(const float* __restrict__ x, unsigned short* __restrict__ xb, int n4) {
    int i = blockIdx.x * blockDim.x + threadIdx.x;
    if (i < n4) {
        float4 v = ((const float4*)x)[i];
        ushort4 o;
        o.x = f2bf_rne(v.x); o.y = f2bf_rne(v.y);
        o.z = f2bf_rne(v.z); o.w = f2bf_rne(v.w);
        ((ushort4*)xb)[i] = o;
    }
}

// ---------------- aggregation: u[v] = sum_e w_e*in[src_e] + dinv[v]^2*in[v] ----------------
// input is a bf16 plane; fp32 accumulate; output split bf16 hi/lo (feeds MFMA GEMM).
// one wave per node; 64 lanes x (D/64) features; edge loop unrolled x4.
template<int D>
__global__ __launch_bounds__(256) void k_agg(const unsigned short* __restrict__ tin,
                      unsigned short* __restrict__ th, unsigned short* __restrict__ tl,
                      const int* __restrict__ row_ptr, const int* __restrict__ csr_src,
                      const float* __restrict__ csr_w, const float* __restrict__ dinv) {
    constexpr int V = D / 64;
    int node = blockIdx.x * 4 + (threadIdx.x >> 6);
    int lane = threadIdx.x & 63;
    float acc[V];
    #pragma unroll
    for (int u = 0; u < V; u++) acc[u] = 0.f;
    int beg = row_ptr[node], end = row_ptr[node + 1];
    int e = beg;
    if constexpr (V == 4) {
        for (; e + 4 <= end; e += 4) {
            int s0 = csr_src[e], s1 = csr_src[e + 1], s2 = csr_src[e + 2], s3 = csr_src[e + 3];
            float w0 = csr_w[e], w1 = csr_w[e + 1], w2 = csr_w[e + 2], w3 = csr_w[e + 3];
            ushort4 r0 = *(const ushort4*)(tin + (size_t)s0 * D + lane * 4);
            ushort4 r1 = *(const ushort4*)(tin + (size_t)s1 * D + lane * 4);
            ushort4 r2 = *(const ushort4*)(tin + (size_t)s2 * D + lane * 4);
            ushort4 r3 = *(const ushort4*)(tin + (size_t)s3 * D + lane * 4);
            acc[0] = fmaf(w0, bf2f(r0.x), fmaf(w1, bf2f(r1.x), fmaf(w2, bf2f(r2.x), fmaf(w3, bf2f(r3.x), acc[0]))));
            acc[1] = fmaf(w0, bf2f(r0.y), fmaf(w1, bf2f(r1.y), fmaf(w2, bf2f(r2.y), fmaf(w3, bf2f(r3.y), acc[1]))));
            acc[2] = fmaf(w0, bf2f(r0.z), fmaf(w1, bf2f(r1.z), fmaf(w2, bf2f(r2.z), fmaf(w3, bf2f(r3.z), acc[2]))));
            acc[3] = fmaf(w0, bf2f(r0.w), fmaf(w1, bf2f(r1.w), fmaf(w2, bf2f(r2.w), fmaf(w3, bf2f(r3.w), acc[3]))));
        }
        for (; e < end; e++) {
            int s0 = csr_src[e];
            float w0 = csr_w[e];
            ushort4 r0 = *(const ushort4*)(tin + (size_t)s0 * D + lane * 4);
            acc[0] = fmaf(w0, bf2f(r0.x), acc[0]);
            acc[1] = fmaf(w0, bf2f(r0.y), acc[1]);
            acc[2] = fmaf(w0, bf2f(r0.z), acc[2]);
            acc[3] = fmaf(w0, bf2f(r0.w), acc[3]);
        }
        float dv = dinv[node];
        float sw = dv * dv;
        ushort4 rv = *(const ushort4*)(tin + (size_t)node * D + lane * 4);
        acc[0] = fmaf(sw, bf2f(rv.x), acc[0]);
        acc[1] = fmaf(sw, bf2f(rv.y), acc[1]);
        acc[2] = fmaf(sw, bf2f(rv.z), acc[2]);
        acc[3] = fmaf(sw, bf2f(rv.w), acc[3]);
        ushort4 h4, l4;
        split_bf16(acc[0], h4.x, l4.x);
        split_bf16(acc[1], h4.y, l4.y);
        split_bf16(acc[2], h4.z, l4.z);
        split_bf16(acc[3], h4.w, l4.w);
        size_t o = (size_t)node * D + lane * 4;
        *(ushort4*)(th + o) = h4;
        *(ushort4*)(tl + o) = l4;
    } else {
        for (; e + 4 <= end; e += 4) {
            int s0 = csr_src[e], s1 = csr_src[e + 1], s2 = csr_src[e + 2], s3 = csr_src[e + 3];
            float w0 = csr_w[e], w1 = csr_w[e + 1], w2 = csr_w[e + 2], w3 = csr_w[e + 3];
            ushort2 r0 = *(const ushort2*)(tin + (size_t)s0 * D + lane * 2);
            ushort2 r1 = *(const ushort2*)(tin + (size_t)s1 * D + lane * 2);
            ushort2 r2 = *(const ushort2*)(tin + (size_t)s2 * D + lane * 2);
            ushort2 r3 = *(const ushort2*)(tin + (size_t)s3 * D + lane * 2);
            acc[0] = fmaf(w0, bf2f(r0.x), fmaf(w1, bf2f(r1.x), fmaf(w2, bf2f(r2.x), fmaf(w3, bf2f(r3.x), acc[0]))));
            acc[1] = fmaf(w0, bf2f(r0.y), fmaf(w1, bf2f(r1.y), fmaf(w2, bf2f(r2.y), fmaf(w3, bf2f(r3.y), acc[1]))));
        }
        for (; e < end; e++) {
            int s0 = csr_src[e];
            float w0 = csr_w[e];
            ushort2 r0 = *(const ushort2*)(tin + (size_t)s0 * D + lane * 2);
            acc[0] = fmaf(w0, bf2f(r0.x), acc[0]);
            acc[1] = fmaf(w0, bf2f(r0.y), acc[1]);
        }
        float dv = dinv[node];
        float sw = dv * dv;
        ushort2 rv = *(const ushort2*)(tin + (size_t)node * D + lane * 2);
        acc[0] = fmaf(sw, bf2f(rv.x), acc[0]);
        acc[1] = fmaf(sw, bf2f(rv.y), acc[1]);
        ushort2 h2, l2;
        split_bf16(acc[0], h2.x, l2.x);
        split_bf16(acc[1], h2.y, l2.y);
        size_t o = (size_t)node * D + lane * 2;
        *(ushort2*)(th + o) = h2;
        *(ushort2*)(tl + o) = l2;
    }
}

// ---------------- split-bf16 MFMA GEMM: C[M x 256] = relu(A * W^T + bias) ----------------
// A given as hi/lo bf16 [M x K]; W as hi/lo bf16 [256 x K] (both K-contiguous, NT).
// Block 256 threads (4 waves), tile BM=128 x BN=64, BK=32. Wave = 64x32 = 4x2 tiles of 16x16.
// A*W ~= Ah*Wh + Ah*Wl + Al*Wh  (Al*Wl dropped, ~2^-16 relative)
// BF_OUT: store result as bf16 plane (feeds next agg); else fp32 (feeds pool).
template<int K, bool BF_OUT>
__global__ __launch_bounds__(256) void k_gemm(const unsigned short* __restrict__ Ah,
        const unsigned short* __restrict__ Al,
        const unsigned short* __restrict__ Wh, const unsigned short* __restrict__ Wl,
        const float* __restrict__ bias, float* __restrict__ C,
        unsigned short* __restrict__ Cb, int M) {
    __shared__ unsigned short lsAh[128 * 32];
    __shared__ unsigned short lsAl[128 * 32];
    __shared__ unsigned short lsBh[64 * 32];
    __shared__ unsigned short lsBl[64 * 32];
    int t = threadIdx.x;
    int bm = blockIdx.x * 128;
    int bn = blockIdx.y * 64;
    int lane = t & 63, wv = t >> 6;
    int wm = (wv & 1) * 64;       // wave m-offset in block
    int wn = (wv >> 1) * 32;      // wave n-offset in block
    int lm = lane & 15, q = lane >> 4;
    // staging roles
    int r4 = t >> 2;   // 0..63
    int c4 = t & 3;    // 16B chunk (8 bf16)
    int ra0 = bm + r4;       if (ra0 >= M) ra0 = M - 1;
    int ra1 = bm + 64 + r4;  if (ra1 >= M) ra1 = M - 1;
    int rb  = bn + r4;       // < 256 always

    f32x4 acc[4][2];
    #pragma unroll
    for (int i = 0; i < 4; i++)
        #pragma unroll
        for (int j = 0; j < 2; j++) acc[i][j] = (f32x4){0.f, 0.f, 0.f, 0.f};

    for (int k0 = 0; k0 < K; k0 += 32) {
        size_t ko = (size_t)k0 + c4 * 8;
        uint4 ah0 = *(const uint4*)(Ah + (size_t)ra0 * K + ko);
        uint4 ah1 = *(const uint4*)(Ah + (size_t)ra1 * K + ko);
        uint4 al0 = *(const uint4*)(Al + (size_t)ra0 * K + ko);
        uint4 al1 = *(const uint4*)(Al + (size_t)ra1 * K + ko);
        uint4 bh  = *(const uint4*)(Wh + (size_t)rb * K + ko);
        uint4 bl  = *(const uint4*)(Wl + (size_t)rb * K + ko);
        __syncthreads();  // previous tile fully consumed
        *(uint4*)&lsAh[(r4) * 32 + c4 * 8] = ah0;
        *(uint4*)&lsAh[(64 + r4) * 32 + c4 * 8] = ah1;
        *(uint4*)&lsAl[(r4) * 32 + c4 * 8] = al0;
        *(uint4*)&lsAl[(64 + r4) * 32 + c4 * 8] = al1;
        *(uint4*)&lsBh[r4 * 32 + c4 * 8] = bh;
        *(uint4*)&lsBl[r4 * 32 + c4 * 8] = bl;
        __syncthreads();  // tile staged
        bf16x8 bfh[2], bfl[2];
        #pragma unroll
        for (int nt = 0; nt < 2; nt++) {
            bfh[nt] = *(const bf16x8*)&lsBh[(wn + nt * 16 + lm) * 32 + q * 8];
            bfl[nt] = *(const bf16x8*)&lsBl[(wn + nt * 16 + lm) * 32 + q * 8];
        }
        #pragma unroll
        for (int mt = 0; mt < 4; mt++) {
            bf16x8 afh = *(const bf16x8*)&lsAh[(wm + mt * 16 + lm) * 32 + q * 8];
            bf16x8 afl = *(const bf16x8*)&lsAl[(wm + mt * 16 + lm) * 32 + q * 8];
            #pragma unroll
            for (int nt = 0; nt < 2; nt++) {
                acc[mt][nt] = __builtin_amdgcn_mfma_f32_16x16x32_bf16(afh, bfh[nt], acc[mt][nt], 0, 0, 0);
                acc[mt][nt] = __builtin_amdgcn_mfma_f32_16x16x32_bf16(afh, bfl[nt], acc[mt][nt], 0, 0, 0);
                acc[mt][nt] = __builtin_amdgcn_mfma_f32_16x16x32_bf16(afl, bfh[nt], acc[mt][nt], 0, 0, 0);
            }
        }
    }
    // epilogue: C/D layout col = lane&15, row = q*4 + r
    #pragma unroll
    for (int mt = 0; mt < 4; mt++) {
        #pragma unroll
        for (int nt = 0; nt < 2; nt++) {
            int col = bn + wn + nt * 16 + lm;
            float bv = bias[col];
            #pragma unroll
            for (int r = 0; r < 4; r++) {
                int row = bm + wm + mt * 16 + q * 4 + r;
                if (row < M) {
                    float v = fmaxf(acc[mt][nt][r] + bv, 0.f);
                    if constexpr (BF_OUT) {
                        Cb[(size_t)row * 256 + col] = f2bf_rne(v);
                    } else {
                        C[(size_t)row * 256 + col] = v;
                    }
                }
            }
        }
    }
}

// ---------------- mean pool over sorted batch ids ----------------
__global__ __launch_bounds__(256) void k_pool(const float* __restrict__ h, const int* __restrict__ batch,
                       float* __restrict__ pooled) {
    int g = blockIdx.x;
    int lo = 0, hi = NN;
    while (lo < hi) { int mid = (lo + hi) >> 1; if (batch[mid] < g) lo = mid + 1; else hi = mid; }
    int start = lo;
    hi = NN;
    while (lo < hi) { int mid = (lo + hi) >> 1; if (batch[mid] < g + 1) lo = mid + 1; else hi = mid; }
    int end = lo;
    int f = threadIdx.x;  // 256 = DH
    float s = 0.f;
    for (int r = start; r < end; r++) s += h[(size_t)r * DH + f];
    int cnt = end - start;
    pooled[g * DH + f] = (cnt > 0) ? s / (float)cnt : 0.f;
}

// ---------------- FC: out[G x 60] = pooled[G x 256] @ Wfc[60 x 256]^T + bfc ----------------
__global__ __launch_bounds__(64) void k_fc(const float* __restrict__ pooled, const float* __restrict__ Wfc,
                    const float* __restrict__ bfc, float* __restrict__ out) {
    __shared__ float p[DH];
    int g = blockIdx.x;
    int t = threadIdx.x;
    for (int i = t; i < DH; i += 64) p[i] = pooled[g * DH + i];
    __syncthreads();
    if (t < NC) {
        float a = bfc[t];
        for (int k = 0; k < DH; k++) a = fmaf(p[k], Wfc[t * DH + k], a);
        out[g * NC + t] = a;
    }
}

extern "C" void kernel_launch(void* const* d_in, const int* in_sizes, int n_in,
                              void* d_out, int out_size, void* d_ws, size_t ws_size,
                              hipStream_t stream) {
    const float* x     = (const float*)d_in[0];
    const int*   ei    = (const int*)d_in[1];
    const int*   batch = (const int*)d_in[2];
    const float* W1 = (const float*)d_in[3];
    const float* b1 = (const float*)d_in[4];
    const float* W2 = (const float*)d_in[5];
    const float* b2 = (const float*)d_in[6];
    const float* W3 = (const float*)d_in[7];
    const float* b3 = (const float*)d_in[8];
    const float* Wfc = (const float*)d_in[9];
    const float* bfc = (const float*)d_in[10];
    float* out = (float*)d_out;

    char* wp = (char*)d_ws;
    auto alloc = [&](size_t bytes) {
        char* p = wp;
        wp += (bytes + 511) & ~(size_t)511;
        return (void*)p;
    };
    int*   icnt    = (int*)alloc((size_t)NN * 4);
    int*   row_ptr = (int*)alloc((size_t)(NN + 1) * 4);
    int*   cursor  = (int*)alloc((size_t)NN * 4);
    int*   psum    = (int*)alloc((size_t)NB * 4);
    int*   poff    = (int*)alloc((size_t)NB * 4);
    int*   csr_src = (int*)alloc((size_t)NE * 4);
    float* csr_w   = (float*)alloc((size_t)NE * 4);
    float* dinv    = (float*)alloc((size_t)NN * 4);
    unsigned short* xb = (unsigned short*)alloc((size_t)NN * DIN * 2);
    unsigned short* th = (unsigned short*)alloc((size_t)NN * DH * 2);
    unsigned short* tl = (unsigned short*)alloc((size_t)NN * DH * 2);
    unsigned short* hb = (unsigned short*)alloc((size_t)NN * DH * 2);
    float* hbuf    = (float*)alloc((size_t)NN * DH * 4);
    unsigned short* w1h = (unsigned short*)alloc((size_t)DH * DIN * 2);
    unsigned short* w1l = (unsigned short*)alloc((size_t)DH * DIN * 2);
    unsigned short* w2h = (unsigned short*)alloc((size_t)DH * DH * 2);
    unsigned short* w2l = (unsigned short*)alloc((size_t)DH * DH * 2);
    unsigned short* w3h = (unsigned short*)alloc((size_t)DH * DH * 2);
    unsigned short* w3l = (unsigned short*)alloc((size_t)DH * DH * 2);
    float* pooled  = (float*)alloc((size_t)NG * DH * 4);

    hipMemsetAsync(icnt, 0, (size_t)NN * 4, stream);
    hipMemsetAsync(cursor, 0, (size_t)NN * 4, stream);

    k_count<<<(NE + 255) / 256, 256, 0, stream>>>(ei + NE, icnt);
    k_dinv<<<(NN + 255) / 256, 256, 0, stream>>>(icnt, dinv);
    k_scan1<<<NB, 256, 0, stream>>>(icnt, psum);
    k_scan2<<<1, 64, 0, stream>>>(psum, poff);
    k_scan3<<<NB, 256, 0, stream>>>(icnt, poff, row_ptr);
    k_fill<<<(NE + 255) / 256, 256, 0, stream>>>(ei, dinv, row_ptr, cursor, csr_src, csr_w);

    k_wsplit<<<(DH * DIN + 255) / 256, 256, 0, stream>>>(W1, w1h, w1l, DH * DIN);
    k_wsplit<<<(DH * DH + 255) / 256, 256, 0, stream>>>(W2, w2h, w2l, DH * DH);
    k_wsplit<<<(DH * DH + 255) / 256, 256, 0, stream>>>(W3, w3h, w3l, DH * DH);
    k_x2bf<<<(NN * DIN / 4 + 255) / 256, 256, 0, stream>>>(x, xb, NN * DIN / 4);

    dim3 gemm_grid((NN + 127) / 128, 4);

    // all layers: h_l = relu((A.h_{l-1}) W^T + b)  [linearity reorder]
    k_agg<128><<<NN / 4, 256, 0, stream>>>(xb, th, tl, row_ptr, csr_src, csr_w, dinv);
    k_gemm<128, true><<<gemm_grid, 256, 0, stream>>>(th, tl, w1h, w1l, b1, nullptr, hb, NN);
    k_agg<256><<<NN / 4, 256, 0, stream>>>(hb, th, tl, row_ptr, csr_src, csr_w, dinv);
    k_gemm<256, true><<<gemm_grid, 256, 0, stream>>>(th, tl, w2h, w2l, b2, nullptr, hb, NN);
    k_agg<256><<<NN / 4, 256, 0, stream>>>(hb, th, tl, row_ptr, csr_src, csr_w, dinv);
    k_gemm<256, false><<<gemm_grid, 256, 0, stream>>>(th, tl, w3h, w3l, b3, hbuf, nullptr, NN);

    k_pool<<<NG, 256, 0, stream>>>(hbuf, batch, pooled);
    k_fc<<<NG, 64, 0, stream>>>(pooled, Wfc, bfc, out);
}

// Round 4
// 360.332 us; speedup vs baseline: 1.6532x; 1.1162x over previous
//
#include <hip/hip_runtime.h>
#include <hip/hip_bf16.h>
#include <cstdint>
#include <cstddef>

#define NN 30000
#define NE 480000
#define NG 128
#define DIN 128
#define DH 256
#define NC 60
#define NB 118  // scan blocks: ceil(30000/256)

typedef __bf16 bf16x8 __attribute__((ext_vector_type(8)));
typedef float f32x4 __attribute__((ext_vector_type(4)));

// ---------------- bf16 helpers (RNE, branchless, finite inputs) ----------------
__device__ __forceinline__ unsigned short f2bf_rne(float f) {
    unsigned int u = __builtin_bit_cast(unsigned int, f);
    u += 0x7fffu + ((u >> 16) & 1u);
    return (unsigned short)(u >> 16);
}
__device__ __forceinline__ float bf2f(unsigned short b) {
    unsigned int u = ((unsigned int)b) << 16;
    return __builtin_bit_cast(float, u);
}
__device__ __forceinline__ void split_bf16(float f, unsigned short& hi, unsigned short& lo) {
    hi = f2bf_rne(f);
    lo = f2bf_rne(f - bf2f(hi));
}

// ---------------- CSR build ----------------
__global__ void k_count(const int* __restrict__ dst, int* __restrict__ icnt) {
    int e = blockIdx.x * blockDim.x + threadIdx.x;
    if (e < NE) atomicAdd(&icnt[dst[e]], 1);
}

__global__ void k_dinv(const int* __restrict__ icnt, float* __restrict__ dinv) {
    int v = blockIdx.x * blockDim.x + threadIdx.x;
    if (v < NN) dinv[v] = rsqrtf((float)(icnt[v] + 1));  // +1 self-loop
}

// scan stage 1: per-block sums of icnt
__global__ __launch_bounds__(256) void k_scan1(const int* __restrict__ icnt, int* __restrict__ psum) {
    __shared__ int ws[4];
    int i = blockIdx.x * 256 + threadIdx.x;
    int lane = threadIdx.x & 63, wv = threadIdx.x >> 6;
    int v = (i < NN) ? icnt[i] : 0;
    #pragma unroll
    for (int off = 32; off > 0; off >>= 1) v += __shfl_down(v, off, 64);
    if (lane == 0) ws[wv] = v;
    __syncthreads();
    if (threadIdx.x == 0) psum[blockIdx.x] = ws[0] + ws[1] + ws[2] + ws[3];
}

// scan stage 2: exclusive scan of NB partial sums (1 wave)
__global__ __launch_bounds__(64) void k_scan2(const int* __restrict__ psum, int* __restrict__ poff) {
    int lane = threadIdx.x;
    int carry = 0;
    for (int base = 0; base < NB; base += 64) {
        int i = base + lane;
        int v = (i < NB) ? psum[i] : 0;
        int s = v;
        #pragma unroll
        for (int off = 1; off < 64; off <<= 1) {
            int n = __shfl_up(s, off, 64);
            if (lane >= off) s += n;
        }
        if (i < NB) poff[i] = carry + s - v;
        carry += __shfl(s, 63, 64);
    }
}

// scan stage 3: row_ptr = poff[b] + exclusive within block
__global__ __launch_bounds__(256) void k_scan3(const int* __restrict__ icnt, const int* __restrict__ poff,
                                               int* __restrict__ row_ptr) {
    __shared__ int ws[4];
    int i = blockIdx.x * 256 + threadIdx.x;
    int lane = threadIdx.x & 63, wv = threadIdx.x >> 6;
    int v = (i < NN) ? icnt[i] : 0;
    int s = v;
    #pragma unroll
    for (int off = 1; off < 64; off <<= 1) {
        int n = __shfl_up(s, off, 64);
        if (lane >= off) s += n;
    }
    if (lane == 63) ws[wv] = s;
    __syncthreads();
    int add = 0;
    for (int j = 0; j < wv; j++) add += ws[j];
    if (i < NN) row_ptr[i] = poff[blockIdx.x] + add + s - v;
    if (blockIdx.x == 0 && threadIdx.x == 0) row_ptr[NN] = NE;
}

__global__ void k_fill(const int* __restrict__ ei, const float* __restrict__ dinv,
                       const int* __restrict__ row_ptr, int* __restrict__ cursor,
                       int* __restrict__ csr_src, float* __restrict__ csr_w) {
    int e = blockIdx.x * blockDim.x + threadIdx.x;
    if (e >= NE) return;
    int s = ei[e];        // edge_index[0]
    int d = ei[NE + e];   // edge_index[1]
    int pos = row_ptr[d] + atomicAdd(&cursor[d], 1);
    csr_src[pos] = s;
    csr_w[pos] = dinv[s] * dinv[d];
}

// ---------------- W split: fp32 -> bf16 hi/lo ----------------
__global__ void k_wsplit(const float* __restrict__ W, unsigned short* __restrict__ Wh,
                         unsigned short* __restrict__ Wl, int n) {
    int i = blockIdx.x * blockDim.x + threadIdx.x;
    if (i < n) split_bf16(W[i], Wh[i], Wl[i]);
}

// ---------------- x: fp32 -> bf16 plane ----------------
__global__ void k_x2bf(const float* __restrict__ x, unsigned short* __restrict__ xb, int n4) {
    int i = blockIdx.x * blockDim.x + threadIdx.x;
    if (i < n4) {
        float4 v = ((const float4*)x)[i];
        ushort4 o;
        o.x = f2bf_rne(v.x); o.y = f2bf_rne(v.y);
        o.z = f2bf_rne(v.z); o.w = f2bf_rne(v.w);
        ((ushort4*)xb)[i] = o;
    }
}

// ---------------- aggregation: u[v] = sum_e w_e*in[src_e] + dinv[v]^2*in[v] ----------------
// input is a bf16 plane; fp32 accumulate; output split bf16 hi/lo (feeds MFMA GEMM).
// one wave per node; 64 lanes x (D/64) features; edge loop unrolled x4.
template<int D>
__global__ __launch_bounds__(256) void k_agg(const unsigned short* __restrict__ tin,
                      unsigned short* __restrict__ th, unsigned short* __restrict__ tl,
                      const int* __restrict__ row_ptr, const int* __restrict__ csr_src,
                      const float* __restrict__ csr_w, const float* __restrict__ dinv) {
    constexpr int V = D / 64;
    int node = blockIdx.x * 4 + (threadIdx.x >> 6);
    int lane = threadIdx.x & 63;
    float acc[V];
    #pragma unroll
    for (int u = 0; u < V; u++) acc[u] = 0.f;
    int beg = row_ptr[node], end = row_ptr[node + 1];
    int e = beg;
    if constexpr (V == 4) {
        for (; e + 4 <= end; e += 4) {
            int s0 = csr_src[e], s1 = csr_src[e + 1], s2 = csr_src[e + 2], s3 = csr_src[e + 3];
            float w0 = csr_w[e], w1 = csr_w[e + 1], w2 = csr_w[e + 2], w3 = csr_w[e + 3];
            ushort4 r0 = *(const ushort4*)(tin + (size_t)s0 * D + lane * 4);
            ushort4 r1 = *(const ushort4*)(tin + (size_t)s1 * D + lane * 4);
            ushort4 r2 = *(const ushort4*)(tin + (size_t)s2 * D + lane * 4);
            ushort4 r3 = *(const ushort4*)(tin + (size_t)s3 * D + lane * 4);
            acc[0] = fmaf(w0, bf2f(r0.x), fmaf(w1, bf2f(r1.x), fmaf(w2, bf2f(r2.x), fmaf(w3, bf2f(r3.x), acc[0]))));
            acc[1] = fmaf(w0, bf2f(r0.y), fmaf(w1, bf2f(r1.y), fmaf(w2, bf2f(r2.y), fmaf(w3, bf2f(r3.y), acc[1]))));
            acc[2] = fmaf(w0, bf2f(r0.z), fmaf(w1, bf2f(r1.z), fmaf(w2, bf2f(r2.z), fmaf(w3, bf2f(r3.z), acc[2]))));
            acc[3] = fmaf(w0, bf2f(r0.w), fmaf(w1, bf2f(r1.w), fmaf(w2, bf2f(r2.w), fmaf(w3, bf2f(r3.w), acc[3]))));
        }
        for (; e < end; e++) {
            int s0 = csr_src[e];
            float w0 = csr_w[e];
            ushort4 r0 = *(const ushort4*)(tin + (size_t)s0 * D + lane * 4);
            acc[0] = fmaf(w0, bf2f(r0.x), acc[0]);
            acc[1] = fmaf(w0, bf2f(r0.y), acc[1]);
            acc[2] = fmaf(w0, bf2f(r0.z), acc[2]);
            acc[3] = fmaf(w0, bf2f(r0.w), acc[3]);
        }
        float dv = dinv[node];
        float sw = dv * dv;
        ushort4 rv = *(const ushort4*)(tin + (size_t)node * D + lane * 4);
        acc[0] = fmaf(sw, bf2f(rv.x), acc[0]);
        acc[1] = fmaf(sw, bf2f(rv.y), acc[1]);
        acc[2] = fmaf(sw, bf2f(rv.z), acc[2]);
        acc[3] = fmaf(sw, bf2f(rv.w), acc[3]);
        ushort4 h4, l4;
        split_bf16(acc[0], h4.x, l4.x);
        split_bf16(acc[1], h4.y, l4.y);
        split_bf16(acc[2], h4.z, l4.z);
        split_bf16(acc[3], h4.w, l4.w);
        size_t o = (size_t)node * D + lane * 4;
        *(ushort4*)(th + o) = h4;
        *(ushort4*)(tl + o) = l4;
    } else {
        for (; e + 4 <= end; e += 4) {
            int s0 = csr_src[e], s1 = csr_src[e + 1], s2 = csr_src[e + 2], s3 = csr_src[e + 3];
            float w0 = csr_w[e], w1 = csr_w[e + 1], w2 = csr_w[e + 2], w3 = csr_w[e + 3];
            ushort2 r0 = *(const ushort2*)(tin + (size_t)s0 * D + lane * 2);
            ushort2 r1 = *(const ushort2*)(tin + (size_t)s1 * D + lane * 2);
            ushort2 r2 = *(const ushort2*)(tin + (size_t)s2 * D + lane * 2);
            ushort2 r3 = *(const ushort2*)(tin + (size_t)s3 * D + lane * 2);
            acc[0] = fmaf(w0, bf2f(r0.x), fmaf(w1, bf2f(r1.x), fmaf(w2, bf2f(r2.x), fmaf(w3, bf2f(r3.x), acc[0]))));
            acc[1] = fmaf(w0, bf2f(r0.y), fmaf(w1, bf2f(r1.y), fmaf(w2, bf2f(r2.y), fmaf(w3, bf2f(r3.y), acc[1]))));
        }
        for (; e < end; e++) {
            int s0 = csr_src[e];
            float w0 = csr_w[e];
            ushort2 r0 = *(const ushort2*)(tin + (size_t)s0 * D + lane * 2);
            acc[0] = fmaf(w0, bf2f(r0.x), acc[0]);
            acc[1] = fmaf(w0, bf2f(r0.y), acc[1]);
        }
        float dv = dinv[node];
        float sw = dv * dv;
        ushort2 rv = *(const ushort2*)(tin + (size_t)node * D + lane * 2);
        acc[0] = fmaf(sw, bf2f(rv.x), acc[0]);
        acc[1] = fmaf(sw, bf2f(rv.y), acc[1]);
        ushort2 h2, l2;
        split_bf16(acc[0], h2.x, l2.x);
        split_bf16(acc[1], h2.y, l2.y);
        size_t o = (size_t)node * D + lane * 2;
        *(ushort2*)(th + o) = h2;
        *(ushort2*)(tl + o) = l2;
    }
}

// ---------------- split-bf16 MFMA GEMM: C[M x 256] = relu(A * W^T + bias) ----------------
// A given as hi/lo bf16 [M x K]; W as hi/lo bf16 [256 x K] (both K-contiguous, NT).
// Block 256 threads (4 waves), tile BM=128 x BN=64, BK=32. Wave = 64x32 = 4x2 tiles of 16x16.
// A*W ~= Ah*Wh + Ah*Wl + Al*Wh  (Al*Wl dropped, ~2^-16 relative)
// BF_OUT: store result as bf16 plane (feeds next agg); else fp32 (feeds pool).
template<int K, bool BF_OUT>
__global__ __launch_bounds__(256) void k_gemm(const unsigned short* __restrict__ Ah,
        const unsigned short* __restrict__ Al,
        const unsigned short* __restrict__ Wh, const unsigned short* __restrict__ Wl,
        const float* __restrict__ bias, float* __restrict__ C,
        unsigned short* __restrict__ Cb, int M) {
    __shared__ unsigned short lsAh[128 * 32];
    __shared__ unsigned short lsAl[128 * 32];
    __shared__ unsigned short lsBh[64 * 32];
    __shared__ unsigned short lsBl[64 * 32];
    int t = threadIdx.x;
    int bm = blockIdx.x * 128;
    int bn = blockIdx.y * 64;
    int lane = t & 63, wv = t >> 6;
    int wm = (wv & 1) * 64;       // wave m-offset in block
    int wn = (wv >> 1) * 32;      // wave n-offset in block
    int lm = lane & 15, q = lane >> 4;
    // staging roles
    int r4 = t >> 2;   // 0..63
    int c4 = t & 3;    // 16B chunk (8 bf16)
    int ra0 = bm + r4;       if (ra0 >= M) ra0 = M - 1;
    int ra1 = bm + 64 + r4;  if (ra1 >= M) ra1 = M - 1;
    int rb  = bn + r4;       // < 256 always

    f32x4 acc[4][2];
    #pragma unroll
    for (int i = 0; i < 4; i++)
        #pragma unroll
        for (int j = 0; j < 2; j++) acc[i][j] = (f32x4){0.f, 0.f, 0.f, 0.f};

    for (int k0 = 0; k0 < K; k0 += 32) {
        size_t ko = (size_t)k0 + c4 * 8;
        uint4 ah0 = *(const uint4*)(Ah + (size_t)ra0 * K + ko);
        uint4 ah1 = *(const uint4*)(Ah + (size_t)ra1 * K + ko);
        uint4 al0 = *(const uint4*)(Al + (size_t)ra0 * K + ko);
        uint4 al1 = *(const uint4*)(Al + (size_t)ra1 * K + ko);
        uint4 bh  = *(const uint4*)(Wh + (size_t)rb * K + ko);
        uint4 bl  = *(const uint4*)(Wl + (size_t)rb * K + ko);
        __syncthreads();  // previous tile fully consumed
        *(uint4*)&lsAh[(r4) * 32 + c4 * 8] = ah0;
        *(uint4*)&lsAh[(64 + r4) * 32 + c4 * 8] = ah1;
        *(uint4*)&lsAl[(r4) * 32 + c4 * 8] = al0;
        *(uint4*)&lsAl[(64 + r4) * 32 + c4 * 8] = al1;
        *(uint4*)&lsBh[r4 * 32 + c4 * 8] = bh;
        *(uint4*)&lsBl[r4 * 32 + c4 * 8] = bl;
        __syncthreads();  // tile staged
        bf16x8 bfh[2], bfl[2];
        #pragma unroll
        for (int nt = 0; nt < 2; nt++) {
            bfh[nt] = *(const bf16x8*)&lsBh[(wn + nt * 16 + lm) * 32 + q * 8];
            bfl[nt] = *(const bf16x8*)&lsBl[(wn + nt * 16 + lm) * 32 + q * 8];
        }
        #pragma unroll
        for (int mt = 0; mt < 4; mt++) {
            bf16x8 afh = *(const bf16x8*)&lsAh[(wm + mt * 16 + lm) * 32 + q * 8];
            bf16x8 afl = *(const bf16x8*)&lsAl[(wm + mt * 16 + lm) * 32 + q * 8];
            #pragma unroll
            for (int nt = 0; nt < 2; nt++) {
                acc[mt][nt] = __builtin_amdgcn_mfma_f32_16x16x32_bf16(afh, bfh[nt], acc[mt][nt], 0, 0, 0);
                acc[mt][nt] = __builtin_amdgcn_mfma_f32_16x16x32_bf16(afh, bfl[nt], acc[mt][nt], 0, 0, 0);
                acc[mt][nt] = __builtin_amdgcn_mfma_f32_16x16x32_bf16(afl, bfh[nt], acc[mt][nt], 0, 0, 0);
            }
        }
    }
    // epilogue: C/D layout col = lane&15, row = q*4 + r
    #pragma unroll
    for (int mt = 0; mt < 4; mt++) {
        #pragma unroll
        for (int nt = 0; nt < 2; nt++) {
            int col = bn + wn + nt * 16 + lm;
            float bv = bias[col];
            #pragma unroll
            for (int r = 0; r < 4; r++) {
                int row = bm + wm + mt * 16 + q * 4 + r;
                if (row < M) {
                    float v = fmaxf(acc[mt][nt][r] + bv, 0.f);
                    if constexpr (BF_OUT) {
                        Cb[(size_t)row * 256 + col] = f2bf_rne(v);
                    } else {
                        C[(size_t)row * 256 + col] = v;
                    }
                }
            }
        }
    }
}

// ---------------- pool stage 1: chunked segmented sum (batch sorted) ----------------
// block = 64 consecutive rows x 256 features; run-accumulate per graph id, atomic flush per segment
__global__ __launch_bounds__(256) void k_pool(const float* __restrict__ h, const int* __restrict__ batch,
                       float* __restrict__ sums) {
    int f = threadIdx.x;
    int r0 = blockIdx.x * 64;
    int r1 = min(r0 + 64, NN);
    float acc = 0.f;
    int cur = batch[r0];
    for (int r = r0; r < r1; r++) {
        int g = batch[r];  // uniform across block; L1 broadcast
        if (g != cur) {
            atomicAdd(&sums[cur * DH + f], acc);
            acc = 0.f;
            cur = g;
        }
        acc += h[(size_t)r * DH + f];
    }
    atomicAdd(&sums[cur * DH + f], acc);
}

// ---------------- FC: out[G x 60] = (sums[g]/cnt) @ Wfc[60 x 256]^T + bfc ----------------
__global__ __launch_bounds__(64) void k_fc(const float* __restrict__ sums, const int* __restrict__ batch,
                    const float* __restrict__ Wfc, const float* __restrict__ bfc,
                    float* __restrict__ out) {
    __shared__ float p[DH];
    int g = blockIdx.x;
    int t = threadIdx.x;
    // count rows of graph g (batch sorted): redundant binary search per thread
    int lo = 0, hi = NN;
    while (lo < hi) { int mid = (lo + hi) >> 1; if (batch[mid] < g) lo = mid + 1; else hi = mid; }
    int start = lo;
    hi = NN;
    while (lo < hi) { int mid = (lo + hi) >> 1; if (batch[mid] < g + 1) lo = mid + 1; else hi = mid; }
    int cnt = lo - start;
    float inv = (cnt > 0) ? 1.f / (float)cnt : 0.f;
    for (int i = t; i < DH; i += 64) p[i] = sums[g * DH + i] * inv;
    __syncthreads();
    if (t < NC) {
        float a = bfc[t];
        for (int k = 0; k < DH; k++) a = fmaf(p[k], Wfc[t * DH + k], a);
        out[g * NC + t] = a;
    }
}

extern "C" void kernel_launch(void* const* d_in, const int* in_sizes, int n_in,
                              void* d_out, int out_size, void* d_ws, size_t ws_size,
                              hipStream_t stream) {
    const float* x     = (const float*)d_in[0];
    const int*   ei    = (const int*)d_in[1];
    const int*   batch = (const int*)d_in[2];
    const float* W1 = (const float*)d_in[3];
    const float* b1 = (const float*)d_in[4];
    const float* W2 = (const float*)d_in[5];
    const float* b2 = (const float*)d_in[6];
    const float* W3 = (const float*)d_in[7];
    const float* b3 = (const float*)d_in[8];
    const float* Wfc = (const float*)d_in[9];
    const float* bfc = (const float*)d_in[10];
    float* out = (float*)d_out;

    char* wp = (char*)d_ws;
    auto alloc = [&](size_t bytes) {
        char* p = wp;
        wp += (bytes + 511) & ~(size_t)511;
        return (void*)p;
    };
    int*   icnt    = (int*)alloc((size_t)NN * 4);
    int*   row_ptr = (int*)alloc((size_t)(NN + 1) * 4);
    int*   cursor  = (int*)alloc((size_t)NN * 4);
    int*   psum    = (int*)alloc((size_t)NB * 4);
    int*   poff    = (int*)alloc((size_t)NB * 4);
    int*   csr_src = (int*)alloc((size_t)NE * 4);
    float* csr_w   = (float*)alloc((size_t)NE * 4);
    float* dinv    = (float*)alloc((size_t)NN * 4);
    unsigned short* xb = (unsigned short*)alloc((size_t)NN * DIN * 2);
    unsigned short* th = (unsigned short*)alloc((size_t)NN * DH * 2);
    unsigned short* tl = (unsigned short*)alloc((size_t)NN * DH * 2);
    unsigned short* hb = (unsigned short*)alloc((size_t)NN * DH * 2);
    float* hbuf    = (float*)alloc((size_t)NN * DH * 4);
    unsigned short* w1h = (unsigned short*)alloc((size_t)DH * DIN * 2);
    unsigned short* w1l = (unsigned short*)alloc((size_t)DH * DIN * 2);
    unsigned short* w2h = (unsigned short*)alloc((size_t)DH * DH * 2);
    unsigned short* w2l = (unsigned short*)alloc((size_t)DH * DH * 2);
    unsigned short* w3h = (unsigned short*)alloc((size_t)DH * DH * 2);
    unsigned short* w3l = (unsigned short*)alloc((size_t)DH * DH * 2);
    float* sums    = (float*)alloc((size_t)NG * DH * 4);

    hipMemsetAsync(icnt, 0, (size_t)NN * 4, stream);
    hipMemsetAsync(cursor, 0, (size_t)NN * 4, stream);
    hipMemsetAsync(sums, 0, (size_t)NG * DH * 4, stream);

    k_count<<<(NE + 255) / 256, 256, 0, stream>>>(ei + NE, icnt);
    k_dinv<<<(NN + 255) / 256, 256, 0, stream>>>(icnt, dinv);
    k_scan1<<<NB, 256, 0, stream>>>(icnt, psum);
    k_scan2<<<1, 64, 0, stream>>>(psum, poff);
    k_scan3<<<NB, 256, 0, stream>>>(icnt, poff, row_ptr);
    k_fill<<<(NE + 255) / 256, 256, 0, stream>>>(ei, dinv, row_ptr, cursor, csr_src, csr_w);

    k_wsplit<<<(DH * DIN + 255) / 256, 256, 0, stream>>>(W1, w1h, w1l, DH * DIN);
    k_wsplit<<<(DH * DH + 255) / 256, 256, 0, stream>>>(W2, w2h, w2l, DH * DH);
    k_wsplit<<<(DH * DH + 255) / 256, 256, 0, stream>>>(W3, w3h, w3l, DH * DH);
    k_x2bf<<<(NN * DIN / 4 + 255) / 256, 256, 0, stream>>>(x, xb, NN * DIN / 4);

    dim3 gemm_grid((NN + 127) / 128, 4);

    // all layers: h_l = relu((A.h_{l-1}) W^T + b)  [linearity reorder]
    k_agg<128><<<NN / 4, 256, 0, stream>>>(xb, th, tl, row_ptr, csr_src, csr_w, dinv);
    k_gemm<128, true><<<gemm_grid, 256, 0, stream>>>(th, tl, w1h, w1l, b1, nullptr, hb, NN);
    k_agg<256><<<NN / 4, 256, 0, stream>>>(hb, th, tl, row_ptr, csr_src, csr_w, dinv);
    k_gemm<256, true><<<gemm_grid, 256, 0, stream>>>(th, tl, w2h, w2l, b2, nullptr, hb, NN);
    k_agg<256><<<NN / 4, 256, 0, stream>>>(hb, th, tl, row_ptr, csr_src, csr_w, dinv);
    k_gemm<256, false><<<gemm_grid, 256, 0, stream>>>(th, tl, w3h, w3l, b3, hbuf, nullptr, NN);

    k_pool<<<(NN + 63) / 64, 256, 0, stream>>>(hbuf, batch, sums);
    k_fc<<<NG, 64, 0, stream>>>(sums, batch, Wfc, bfc, out);
}

// Round 5
// 332.763 us; speedup vs baseline: 1.7902x; 1.0829x over previous
//
#include <hip/hip_runtime.h>
#include <hip/hip_bf16.h>
#include <cstdint>
#include <cstddef>
#include <type_traits>

#define NN 30000
#define NE 480000
#define NG 128
#define DIN 128
#define DH 256
#define NC 60
#define NB 118  // scan blocks: ceil(30000/256)

typedef _Float16 f16x8 __attribute__((ext_vector_type(8)));
typedef _Float16 half4_t __attribute__((ext_vector_type(4)));
typedef _Float16 half2_t __attribute__((ext_vector_type(2)));
typedef float f32x4 __attribute__((ext_vector_type(4)));

// ---------------- CSR build ----------------
__global__ void k_count(const int* __restrict__ dst, int* __restrict__ icnt) {
    int e = blockIdx.x * blockDim.x + threadIdx.x;
    if (e < NE) atomicAdd(&icnt[dst[e]], 1);
}

__global__ void k_dinv(const int* __restrict__ icnt, float* __restrict__ dinv) {
    int v = blockIdx.x * blockDim.x + threadIdx.x;
    if (v < NN) dinv[v] = rsqrtf((float)(icnt[v] + 1));  // +1 self-loop
}

// scan stage 1: per-block sums of icnt
__global__ __launch_bounds__(256) void k_scan1(const int* __restrict__ icnt, int* __restrict__ psum) {
    __shared__ int ws[4];
    int i = blockIdx.x * 256 + threadIdx.x;
    int lane = threadIdx.x & 63, wv = threadIdx.x >> 6;
    int v = (i < NN) ? icnt[i] : 0;
    #pragma unroll
    for (int off = 32; off > 0; off >>= 1) v += __shfl_down(v, off, 64);
    if (lane == 0) ws[wv] = v;
    __syncthreads();
    if (threadIdx.x == 0) psum[blockIdx.x] = ws[0] + ws[1] + ws[2] + ws[3];
}

// scan stage 2: exclusive scan of NB partial sums (1 wave)
__global__ __launch_bounds__(64) void k_scan2(const int* __restrict__ psum, int* __restrict__ poff) {
    int lane = threadIdx.x;
    int carry = 0;
    for (int base = 0; base < NB; base += 64) {
        int i = base + lane;
        int v = (i < NB) ? psum[i] : 0;
        int s = v;
        #pragma unroll
        for (int off = 1; off < 64; off <<= 1) {
            int n = __shfl_up(s, off, 64);
            if (lane >= off) s += n;
        }
        if (i < NB) poff[i] = carry + s - v;
        carry += __shfl(s, 63, 64);
    }
}

// scan stage 3: row_ptr = poff[b] + exclusive within block
__global__ __launch_bounds__(256) void k_scan3(const int* __restrict__ icnt, const int* __restrict__ poff,
                                               int* __restrict__ row_ptr) {
    __shared__ int ws[4];
    int i = blockIdx.x * 256 + threadIdx.x;
    int lane = threadIdx.x & 63, wv = threadIdx.x >> 6;
    int v = (i < NN) ? icnt[i] : 0;
    int s = v;
    #pragma unroll
    for (int off = 1; off < 64; off <<= 1) {
        int n = __shfl_up(s, off, 64);
        if (lane >= off) s += n;
    }
    if (lane == 63) ws[wv] = s;
    __syncthreads();
    int add = 0;
    for (int j = 0; j < wv; j++) add += ws[j];
    if (i < NN) row_ptr[i] = poff[blockIdx.x] + add + s - v;
    if (blockIdx.x == 0 && threadIdx.x == 0) row_ptr[NN] = NE;
}

__global__ void k_fill(const int* __restrict__ ei, const float* __restrict__ dinv,
                       const int* __restrict__ row_ptr, int* __restrict__ cursor,
                       int* __restrict__ csr_src, float* __restrict__ csr_w) {
    int e = blockIdx.x * blockDim.x + threadIdx.x;
    if (e >= NE) return;
    int s = ei[e];        // edge_index[0]
    int d = ei[NE + e];   // edge_index[1]
    int pos = row_ptr[d] + atomicAdd(&cursor[d], 1);
    csr_src[pos] = s;
    csr_w[pos] = dinv[s] * dinv[d];
}

// ---------------- W split: fp32 -> fp16 hi + fp16 residual ----------------
__global__ void k_wsplit(const float* __restrict__ W, _Float16* __restrict__ Wh,
                         _Float16* __restrict__ Wl, int n) {
    int i = blockIdx.x * blockDim.x + threadIdx.x;
    if (i < n) {
        float w = W[i];
        _Float16 h = (_Float16)w;
        Wh[i] = h;
        Wl[i] = (_Float16)(w - (float)h);
    }
}

// ---------------- x: fp32 -> fp16 plane ----------------
__global__ void k_x2h(const float* __restrict__ x, _Float16* __restrict__ xh, int n4) {
    int i = blockIdx.x * blockDim.x + threadIdx.x;
    if (i < n4) {
        float4 v = ((const float4*)x)[i];
        half4_t o;
        o[0] = (_Float16)v.x; o[1] = (_Float16)v.y;
        o[2] = (_Float16)v.z; o[3] = (_Float16)v.w;
        ((half4_t*)xh)[i] = o;
    }
}

// ---------------- aggregation: u[v] = sum_e w_e*in[src_e] + dinv[v]^2*in[v] ----------------
// fp16 plane in, fp32 accumulate, fp16 plane out. one wave per node; edge loop unrolled x8.
template<int D>
__global__ __launch_bounds__(256) void k_agg(const _Float16* __restrict__ tin,
                      _Float16* __restrict__ tout,
                      const int* __restrict__ row_ptr, const int* __restrict__ csr_src,
                      const float* __restrict__ csr_w, const float* __restrict__ dinv) {
    constexpr int V = D / 64;
    using vec_t = std::conditional_t<V == 4, half4_t, half2_t>;
    int node = blockIdx.x * 4 + (threadIdx.x >> 6);
    int lane = threadIdx.x & 63;
    const _Float16* base = tin + lane * V;
    float acc[V];
    #pragma unroll
    for (int u = 0; u < V; u++) acc[u] = 0.f;
    int beg = row_ptr[node], end = row_ptr[node + 1];
    int e = beg;
    for (; e + 8 <= end; e += 8) {
        int s[8]; float w[8];
        #pragma unroll
        for (int j = 0; j < 8; j++) { s[j] = csr_src[e + j]; w[j] = csr_w[e + j]; }
        vec_t r[8];
        #pragma unroll
        for (int j = 0; j < 8; j++) r[j] = *(const vec_t*)(base + (size_t)s[j] * D);
        #pragma unroll
        for (int j = 0; j < 8; j++)
            #pragma unroll
            for (int u = 0; u < V; u++) acc[u] = fmaf(w[j], (float)r[j][u], acc[u]);
    }
    for (; e < end; e++) {
        int s0 = csr_src[e];
        float w0 = csr_w[e];
        vec_t r0 = *(const vec_t*)(base + (size_t)s0 * D);
        #pragma unroll
        for (int u = 0; u < V; u++) acc[u] = fmaf(w0, (float)r0[u], acc[u]);
    }
    float dv = dinv[node];
    float sw = dv * dv;
    vec_t rv = *(const vec_t*)(base + (size_t)node * D);
    #pragma unroll
    for (int u = 0; u < V; u++) acc[u] = fmaf(sw, (float)rv[u], acc[u]);
    vec_t o;
    #pragma unroll
    for (int u = 0; u < V; u++) o[u] = (_Float16)acc[u];
    *(vec_t*)(tout + (size_t)node * D + lane * V) = o;
}

// ---------------- fp16 MFMA GEMM: C[M x 256] = relu(A * W^T + bias) ----------------
// A fp16 [M x K]; W split fp16 hi/lo [256 x K] (K-contiguous, NT).
// A*W = A*Wh + A*Wl  (W at ~2^-22, A at 2^-11 — dominated by A storage rounding)
// Block 256 threads (4 waves), tile BM=128 x BN=64, BK=32. Wave = 64x32 = 4x2 tiles of 16x16.
// LDS rows padded to 40 halves (80 B) to break bank aliasing on ds_read_b128.
// F16_OUT: store result as fp16 plane (feeds next agg); else fp32 (feeds pool).
template<int K, bool F16_OUT>
__global__ __launch_bounds__(256) void k_gemm(const _Float16* __restrict__ A,
        const _Float16* __restrict__ Wh, const _Float16* __restrict__ Wl,
        const float* __restrict__ bias, float* __restrict__ C,
        _Float16* __restrict__ Cb, int M) {
    __shared__ _Float16 lsA[128 * 40];
    __shared__ _Float16 lsBh[64 * 40];
    __shared__ _Float16 lsBl[64 * 40];
    int t = threadIdx.x;
    int bm = blockIdx.x * 128;
    int bn = blockIdx.y * 64;
    int lane = t & 63, wv = t >> 6;
    int wm = (wv & 1) * 64;       // wave m-offset in block
    int wn = (wv >> 1) * 32;      // wave n-offset in block
    int lm = lane & 15, q = lane >> 4;
    // staging roles
    int r4 = t >> 2;   // 0..63
    int c4 = t & 3;    // 16B chunk (8 halves)
    int ra0 = bm + r4;       if (ra0 >= M) ra0 = M - 1;
    int ra1 = bm + 64 + r4;  if (ra1 >= M) ra1 = M - 1;
    int rb  = bn + r4;       // < 256 always

    f32x4 acc[4][2];
    #pragma unroll
    for (int i = 0; i < 4; i++)
        #pragma unroll
        for (int j = 0; j < 2; j++) acc[i][j] = (f32x4){0.f, 0.f, 0.f, 0.f};

    for (int k0 = 0; k0 < K; k0 += 32) {
        size_t ko = (size_t)k0 + c4 * 8;
        uint4 a0 = *(const uint4*)(A + (size_t)ra0 * K + ko);
        uint4 a1 = *(const uint4*)(A + (size_t)ra1 * K + ko);
        uint4 bh = *(const uint4*)(Wh + (size_t)rb * K + ko);
        uint4 bl = *(const uint4*)(Wl + (size_t)rb * K + ko);
        __syncthreads();  // previous tile fully consumed
        *(uint4*)&lsA[r4 * 40 + c4 * 8] = a0;
        *(uint4*)&lsA[(64 + r4) * 40 + c4 * 8] = a1;
        *(uint4*)&lsBh[r4 * 40 + c4 * 8] = bh;
        *(uint4*)&lsBl[r4 * 40 + c4 * 8] = bl;
        __syncthreads();  // tile staged
        f16x8 bfh[2], bfl[2];
        #pragma unroll
        for (int nt = 0; nt < 2; nt++) {
            bfh[nt] = *(const f16x8*)&lsBh[(wn + nt * 16 + lm) * 40 + q * 8];
            bfl[nt] = *(const f16x8*)&lsBl[(wn + nt * 16 + lm) * 40 + q * 8];
        }
        #pragma unroll
        for (int mt = 0; mt < 4; mt++) {
            f16x8 af = *(const f16x8*)&lsA[(wm + mt * 16 + lm) * 40 + q * 8];
            #pragma unroll
            for (int nt = 0; nt < 2; nt++) {
                acc[mt][nt] = __builtin_amdgcn_mfma_f32_16x16x32_f16(af, bfh[nt], acc[mt][nt], 0, 0, 0);
                acc[mt][nt] = __builtin_amdgcn_mfma_f32_16x16x32_f16(af, bfl[nt], acc[mt][nt], 0, 0, 0);
            }
        }
    }
    // epilogue: C/D layout col = lane&15, row = q*4 + r
    #pragma unroll
    for (int mt = 0; mt < 4; mt++) {
        #pragma unroll
        for (int nt = 0; nt < 2; nt++) {
            int col = bn + wn + nt * 16 + lm;
            float bv = bias[col];
            #pragma unroll
            for (int r = 0; r < 4; r++) {
                int row = bm + wm + mt * 16 + q * 4 + r;
                if (row < M) {
                    float v = fmaxf(acc[mt][nt][r] + bv, 0.f);
                    if constexpr (F16_OUT) {
                        Cb[(size_t)row * 256 + col] = (_Float16)v;
                    } else {
                        C[(size_t)row * 256 + col] = v;
                    }
                }
            }
        }
    }
}

// ---------------- pool stage 1: chunked segmented sum (batch sorted) ----------------
// block = 64 consecutive rows x 256 features; run-accumulate per graph id, atomic flush per segment
__global__ __launch_bounds__(256) void k_pool(const float* __restrict__ h, const int* __restrict__ batch,
                       float* __restrict__ sums) {
    int f = threadIdx.x;
    int r0 = blockIdx.x * 64;
    int r1 = min(r0 + 64, NN);
    float acc = 0.f;
    int cur = batch[r0];
    for (int r = r0; r < r1; r++) {
        int g = batch[r];  // uniform across block; L1 broadcast
        if (g != cur) {
            atomicAdd(&sums[cur * DH + f], acc);
            acc = 0.f;
            cur = g;
        }
        acc += h[(size_t)r * DH + f];
    }
    atomicAdd(&sums[cur * DH + f], acc);
}

// ---------------- FC: out[G x 60] = (sums[g]/cnt) @ Wfc[60 x 256]^T + bfc ----------------
__global__ __launch_bounds__(64) void k_fc(const float* __restrict__ sums, const int* __restrict__ batch,
                    const float* __restrict__ Wfc, const float* __restrict__ bfc,
                    float* __restrict__ out) {
    __shared__ float p[DH];
    int g = blockIdx.x;
    int t = threadIdx.x;
    // count rows of graph g (batch sorted): redundant binary search per thread
    int lo = 0, hi = NN;
    while (lo < hi) { int mid = (lo + hi) >> 1; if (batch[mid] < g) lo = mid + 1; else hi = mid; }
    int start = lo;
    hi = NN;
    while (lo < hi) { int mid = (lo + hi) >> 1; if (batch[mid] < g + 1) lo = mid + 1; else hi = mid; }
    int cnt = lo - start;
    float inv = (cnt > 0) ? 1.f / (float)cnt : 0.f;
    for (int i = t; i < DH; i += 64) p[i] = sums[g * DH + i] * inv;
    __syncthreads();
    if (t < NC) {
        float a = bfc[t];
        for (int k = 0; k < DH; k++) a = fmaf(p[k], Wfc[t * DH + k], a);
        out[g * NC + t] = a;
    }
}

extern "C" void kernel_launch(void* const* d_in, const int* in_sizes, int n_in,
                              void* d_out, int out_size, void* d_ws, size_t ws_size,
                              hipStream_t stream) {
    const float* x     = (const float*)d_in[0];
    const int*   ei    = (const int*)d_in[1];
    const int*   batch = (const int*)d_in[2];
    const float* W1 = (const float*)d_in[3];
    const float* b1 = (const float*)d_in[4];
    const float* W2 = (const float*)d_in[5];
    const float* b2 = (const float*)d_in[6];
    const float* W3 = (const float*)d_in[7];
    const float* b3 = (const float*)d_in[8];
    const float* Wfc = (const float*)d_in[9];
    const float* bfc = (const float*)d_in[10];
    float* out = (float*)d_out;

    char* wp = (char*)d_ws;
    auto alloc = [&](size_t bytes) {
        char* p = wp;
        wp += (bytes + 511) & ~(size_t)511;
        return (void*)p;
    };
    int*   icnt    = (int*)alloc((size_t)NN * 4);
    int*   row_ptr = (int*)alloc((size_t)(NN + 1) * 4);
    int*   cursor  = (int*)alloc((size_t)NN * 4);
    int*   psum    = (int*)alloc((size_t)NB * 4);
    int*   poff    = (int*)alloc((size_t)NB * 4);
    int*   csr_src = (int*)alloc((size_t)NE * 4);
    float* csr_w   = (float*)alloc((size_t)NE * 4);
    float* dinv    = (float*)alloc((size_t)NN * 4);
    _Float16* xh   = (_Float16*)alloc((size_t)NN * DIN * 2);
    _Float16* tb   = (_Float16*)alloc((size_t)NN * DH * 2);   // agg output
    _Float16* hb   = (_Float16*)alloc((size_t)NN * DH * 2);   // gemm fp16 output
    float* hbuf    = (float*)alloc((size_t)NN * DH * 4);      // final layer fp32
    _Float16* w1h = (_Float16*)alloc((size_t)DH * DIN * 2);
    _Float16* w1l = (_Float16*)alloc((size_t)DH * DIN * 2);
    _Float16* w2h = (_Float16*)alloc((size_t)DH * DH * 2);
    _Float16* w2l = (_Float16*)alloc((size_t)DH * DH * 2);
    _Float16* w3h = (_Float16*)alloc((size_t)DH * DH * 2);
    _Float16* w3l = (_Float16*)alloc((size_t)DH * DH * 2);
    float* sums    = (float*)alloc((size_t)NG * DH * 4);

    hipMemsetAsync(icnt, 0, (size_t)NN * 4, stream);
    hipMemsetAsync(cursor, 0, (size_t)NN * 4, stream);
    hipMemsetAsync(sums, 0, (size_t)NG * DH * 4, stream);

    k_count<<<(NE + 255) / 256, 256, 0, stream>>>(ei + NE, icnt);
    k_dinv<<<(NN + 255) / 256, 256, 0, stream>>>(icnt, dinv);
    k_scan1<<<NB, 256, 0, stream>>>(icnt, psum);
    k_scan2<<<1, 64, 0, stream>>>(psum, poff);
    k_scan3<<<NB, 256, 0, stream>>>(icnt, poff, row_ptr);
    k_fill<<<(NE + 255) / 256, 256, 0, stream>>>(ei, dinv, row_ptr, cursor, csr_src, csr_w);

    k_wsplit<<<(DH * DIN + 255) / 256, 256, 0, stream>>>(W1, w1h, w1l, DH * DIN);
    k_wsplit<<<(DH * DH + 255) / 256, 256, 0, stream>>>(W2, w2h, w2l, DH * DH);
    k_wsplit<<<(DH * DH + 255) / 256, 256, 0, stream>>>(W3, w3h, w3l, DH * DH);
    k_x2h<<<(NN * DIN / 4 + 255) / 256, 256, 0, stream>>>(x, xh, NN * DIN / 4);

    dim3 gemm_grid((NN + 127) / 128, 4);

    // all layers: h_l = relu((A.h_{l-1}) W^T + b)  [linearity reorder]
    k_agg<128><<<NN / 4, 256, 0, stream>>>(xh, tb, row_ptr, csr_src, csr_w, dinv);
    k_gemm<128, true><<<gemm_grid, 256, 0, stream>>>(tb, w1h, w1l, b1, nullptr, hb, NN);
    k_agg<256><<<NN / 4, 256, 0, stream>>>(hb, tb, row_ptr, csr_src, csr_w, dinv);
    k_gemm<256, true><<<gemm_grid, 256, 0, stream>>>(tb, w2h, w2l, b2, nullptr, hb, NN);
    k_agg<256><<<NN / 4, 256, 0, stream>>>(hb, tb, row_ptr, csr_src, csr_w, dinv);
    k_gemm<256, false><<<gemm_grid, 256, 0, stream>>>(tb, w3h, w3l, b3, hbuf, nullptr, NN);

    k_pool<<<(NN + 63) / 64, 256, 0, stream>>>(hbuf, batch, sums);
    k_fc<<<NG, 64, 0, stream>>>(sums, batch, Wfc, bfc, out);
}